// Round 4
// baseline (4504.783 us; speedup 1.0000x reference)
//
#include <hip/hip_runtime.h>
#include <stdint.h>

#define HH 100
#define WW 100
#define NPIX 10000
#define CIN 1024
#define COUT 1024
#define NA 9
#define NANCH 90000
#define PRE 6000
#define POST 300
#define SORTN 131072
#define MASKW 96
#define NW 94
#define K9 9216   // CIN*9

// ---------------------------------------------------------------------------
// Kernel 0: transpose w1 [co][ci*9+tap] -> wt [ci*9+tap][co]. LDS-tiled.
// ---------------------------------------------------------------------------
__global__ __launch_bounds__(256) void wtrans(
    const float* __restrict__ w1, float* __restrict__ wt)
{
    __shared__ float s[32][33];
    const int tx = threadIdx.x & 31;
    const int ty = threadIdx.x >> 5;
    const int kb = blockIdx.x;
    const int cb = blockIdx.y;
#pragma unroll
    for (int i = 0; i < 4; ++i) {
        int co = cb * 32 + ty + i * 8;
        s[ty + i * 8][tx] = w1[(size_t)co * K9 + kb * 32 + tx];
    }
    __syncthreads();
#pragma unroll
    for (int i = 0; i < 4; ++i) {
        int k = kb * 32 + ty + i * 8;
        wt[(size_t)k * COUT + cb * 32 + tx] = s[tx][ty + i * 8];
    }
}

// ---------------------------------------------------------------------------
// Kernel 1: 3x3 conv (1024->1024, SAME) + bias + ReLU. fp32.
// Block: 8x8 px x 256 co, 256 thr. Thread: 16 px (4x4) x 4 co = 64 accs.
// Per-cc LDS (9 w-b128 + 6 x-b128/b64 + staging ~255 cyc) < FMA/4 (288 cyc)
// => VALU-bound. Register prefetch of next iter's global loads.
// ---------------------------------------------------------------------------
__global__ __launch_bounds__(256, 3) void conv3x3_relu(
    const float* __restrict__ x, const float* __restrict__ wt,
    const float* __restrict__ b1, float* __restrict__ y)
{
    __shared__ __align__(16) float xs[2 * 10 * 12];   // [cc][ir 0..9][pitch 12]
    __shared__ __align__(16) float ws[18 * 256];      // [cc*9+tap][256 co]
    const int t     = threadIdx.x;
    const int ptile = blockIdx.x;          // 0..168 (13x13 px tiles)
    const int cog   = blockIdx.y;          // 0..3
    const int ty0 = (ptile / 13) * 8;
    const int tx0 = (ptile % 13) * 8;
    const int co0 = cog * 256;
    const int cg  = t >> 2;                // 0..63 co group
    const int pg  = t & 3;
    const int qr  = (pg >> 1) * 4;         // 0 or 4: local out-row base
    const int qc  = (pg & 1) * 4;          // 0 or 4: local out-col base

    // ---- hoisted x staging (200 elems: 2 cc x 10x10 halo), t<200
    int xsrc = -1, xdst = 0;
    if (t < 200) {
        int cc = t / 100, rem = t % 100;
        int ir = rem / 10, ic = rem % 10;
        int gy = ty0 - 1 + ir, gx = tx0 - 1 + ic;
        xdst = cc * 120 + ir * 12 + ic;
        if (gy >= 0 && gy < HH && gx >= 0 && gx < WW)
            xsrc = cc * NPIX + gy * WW + gx;
    }
    // ---- hoisted w staging: 1152 f4 per 2-ci (18 rows x 256 co), slots e=t+256k
    int woff[5], wsdst[5];
#pragma unroll
    for (int k = 0; k < 5; ++k) {
        int e = t + 256 * k;
        int row = e >> 6, cf4 = (e & 63) * 4;
        woff[k]  = row * COUT + co0 + cf4;   // + ci0*9*COUT at use
        wsdst[k] = row * 256 + cf4;
    }

    float acc[4][4][4];                    // [r][c][co]
#pragma unroll
    for (int r = 0; r < 4; ++r)
#pragma unroll
        for (int c = 0; c < 4; ++c)
#pragma unroll
            for (int j = 0; j < 4; ++j) acc[r][c][j] = 0.f;

    // ---- initial prefetch (iter 0)
    float4 wpre[5];
    float xpre = 0.f;
#pragma unroll
    for (int k = 0; k < 5; ++k)
        if (k < 4 || t < 128) wpre[k] = *(const float4*)&wt[woff[k]];
    if (xsrc >= 0) xpre = x[xsrc];

    for (int ci0 = 0; ci0 < CIN; ci0 += 2) {
        __syncthreads();
        // commit prefetched data to LDS
#pragma unroll
        for (int k = 0; k < 5; ++k)
            if (k < 4 || t < 128) *(float4*)&ws[wsdst[k]] = wpre[k];
        if (t < 200) xs[xdst] = xpre;
        __syncthreads();
        // prefetch next iter (overlaps compute below)
        if (ci0 + 2 < CIN) {
            const float* wp2 = wt + (size_t)(ci0 + 2) * 9 * COUT;
#pragma unroll
            for (int k = 0; k < 5; ++k)
                if (k < 4 || t < 128) wpre[k] = *(const float4*)&wp2[woff[k]];
            if (xsrc >= 0) xpre = x[(size_t)(ci0 + 2) * NPIX + xsrc];
        }
        // compute 2 input channels
#pragma unroll
        for (int cc = 0; cc < 2; ++cc) {
            float xw[6][6];
#pragma unroll
            for (int i = 0; i < 6; ++i) {
                const float* rowp = &xs[cc * 120 + (qr + i) * 12 + qc];
                float4 a = *(const float4*)rowp;
                float2 b = *(const float2*)(rowp + 4);
                xw[i][0] = a.x; xw[i][1] = a.y; xw[i][2] = a.z; xw[i][3] = a.w;
                xw[i][4] = b.x; xw[i][5] = b.y;
            }
#pragma unroll
            for (int kh = 0; kh < 3; ++kh)
#pragma unroll
                for (int kw = 0; kw < 3; ++kw) {
                    float4 wv = *(const float4*)&ws[(cc * 9 + kh * 3 + kw) * 256 + cg * 4];
#pragma unroll
                    for (int r = 0; r < 4; ++r)
#pragma unroll
                        for (int c = 0; c < 4; ++c) {
                            float xv = xw[r + kh][c + kw];
                            acc[r][c][0] += xv * wv.x;
                            acc[r][c][1] += xv * wv.y;
                            acc[r][c][2] += xv * wv.z;
                            acc[r][c][3] += xv * wv.w;
                        }
                }
        }
    }

    // ---- epilogue: bias + relu; store px-f4 per co
    const int gx0 = tx0 + qc;
    if (gx0 < WW) {
        float4 bv = *(const float4*)&b1[co0 + cg * 4];
        const float bj[4] = {bv.x, bv.y, bv.z, bv.w};
#pragma unroll
        for (int r = 0; r < 4; ++r) {
            int gy = ty0 + qr + r;
            if (gy < HH) {
#pragma unroll
                for (int j = 0; j < 4; ++j) {
                    float4 o;
                    o.x = fmaxf(acc[r][0][j] + bj[j], 0.f);
                    o.y = fmaxf(acc[r][1][j] + bj[j], 0.f);
                    o.z = fmaxf(acc[r][2][j] + bj[j], 0.f);
                    o.w = fmaxf(acc[r][3][j] + bj[j], 0.f);
                    *(float4*)&y[(size_t)(co0 + cg * 4 + j) * NPIX + gy * WW + gx0] = o;
                }
            }
        }
    }
}

// ---------------------------------------------------------------------------
// Kernel 2: fused 1x1 heads + sigmoid + box decode + clip + sort-key pack.
// ---------------------------------------------------------------------------
__global__ __launch_bounds__(256) void rpn_head(
    const float* __restrict__ y,
    const float* __restrict__ wcls, const float* __restrict__ bcls,
    const float* __restrict__ wbox, const float* __restrict__ bbox,
    const float* __restrict__ am, const int* __restrict__ ishape,
    float* __restrict__ out_scores, float* __restrict__ out_deltas,
    float4* __restrict__ boxes, unsigned long long* __restrict__ keys)
{
    __shared__ float wlds[8][46];
    const int t = threadIdx.x;
    const int i = blockIdx.x * 256 + t;
    if (blockIdx.x * 256 >= NANCH) {
        if (i < SORTN) keys[i] = 0ull;
        return;
    }
    const int ia = (i < NANCH) ? i : (NANCH - 1);
    const int p = ia / NA, a = ia % NA;
    float acc[5] = {0.f, 0.f, 0.f, 0.f, 0.f};
    for (int c0 = 0; c0 < CIN; c0 += 8) {
        __syncthreads();
        for (int e = t; e < 360; e += 256) {
            int ch = e % 45, cc = e / 45;
            wlds[cc][ch] = (ch < 9) ? wcls[ch * CIN + c0 + cc]
                                    : wbox[(ch - 9) * CIN + c0 + cc];
        }
        __syncthreads();
#pragma unroll
        for (int cc = 0; cc < 8; ++cc) {
            float yv = y[(size_t)(c0 + cc) * NPIX + p];
            acc[0] += yv * wlds[cc][a];
#pragma unroll
            for (int c = 0; c < 4; ++c)
                acc[1 + c] += yv * wlds[cc][9 + 4 * a + c];
        }
    }
    if (i >= NANCH) { if (i < SORTN) keys[i] = 0ull; return; }

    float logit = acc[0] + bcls[a];
    float score = 1.f / (1.f + expf(-logit));
    float d0 = acc[1] + bbox[4 * a + 0];
    float d1 = acc[2] + bbox[4 * a + 1];
    float d2 = acc[3] + bbox[4 * a + 2];
    float d3 = acc[4] + bbox[4 * a + 3];
    out_scores[i] = score;
    out_deltas[i * 4 + 0] = d0;
    out_deltas[i * 4 + 1] = d1;
    out_deltas[i * 4 + 2] = d2;
    out_deltas[i * 4 + 3] = d3;

    float cy = am[i * 4 + 0], cx = am[i * 4 + 1];
    float ah = am[i * 4 + 2], aw = am[i * 4 + 3];
    float ctry = cy + d0 * ah, ctrx = cx + d1 * aw;
    float hh = ah * expf(d2), ww = aw * expf(d3);
    float y1 = ctry - 0.5f * hh, x1 = ctrx - 0.5f * ww;
    float y2 = ctry + 0.5f * hh, x2 = ctrx + 0.5f * ww;
    float imh = (float)ishape[1], imw = (float)ishape[2];
    y1 = fmaxf(y1, 0.f); x1 = fmaxf(x1, 0.f);
    y2 = fminf(y2, imh); x2 = fminf(x2, imw);
    boxes[i] = make_float4(y1, x1, y2, x2);
    unsigned sb = __float_as_uint(score);
    keys[i] = ((unsigned long long)sb << 32) | (unsigned)i;
}

// ---------------------------------------------------------------------------
// Bitonic sort (descending) of SORTN u64 keys.
// ---------------------------------------------------------------------------
__global__ __launch_bounds__(256) void bitonic_local(unsigned long long* keys)
{
    __shared__ unsigned long long s[2048];
    const int base = blockIdx.x * 2048, t = threadIdx.x;
    for (int k = t; k < 2048; k += 256) s[k] = keys[base + k];
    for (int L = 2; L <= 2048; L <<= 1) {
        for (int d = L >> 1; d >= 1; d >>= 1) {
            __syncthreads();
            for (int pr = t; pr < 1024; pr += 256) {
                int i = ((pr & ~(d - 1)) << 1) | (pr & (d - 1));
                int j = i + d;
                bool desc = (((base + i) & L) == 0);
                unsigned long long va = s[i], vb = s[j];
                bool sw = desc ? (va < vb) : (va > vb);
                if (sw) { s[i] = vb; s[j] = va; }
            }
        }
    }
    __syncthreads();
    for (int k = t; k < 2048; k += 256) keys[base + k] = s[k];
}

__global__ __launch_bounds__(256) void bitonic_gpass(unsigned long long* keys, int L, int d)
{
    int pr = blockIdx.x * 256 + threadIdx.x;
    int i = ((pr & ~(d - 1)) << 1) | (pr & (d - 1));
    int j = i + d;
    bool desc = ((i & L) == 0);
    unsigned long long va = keys[i], vb = keys[j];
    bool sw = desc ? (va < vb) : (va > vb);
    if (sw) { keys[i] = vb; keys[j] = va; }
}

__global__ __launch_bounds__(256) void bitonic_lmerge(unsigned long long* keys, int L)
{
    __shared__ unsigned long long s[2048];
    const int base = blockIdx.x * 2048, t = threadIdx.x;
    for (int k = t; k < 2048; k += 256) s[k] = keys[base + k];
    const bool desc = ((base & L) == 0);
    for (int d = 1024; d >= 1; d >>= 1) {
        __syncthreads();
        for (int pr = t; pr < 1024; pr += 256) {
            int i = ((pr & ~(d - 1)) << 1) | (pr & (d - 1));
            int j = i + d;
            unsigned long long va = s[i], vb = s[j];
            bool sw = desc ? (va < vb) : (va > vb);
            if (sw) { s[i] = vb; s[j] = va; }
        }
    }
    __syncthreads();
    for (int k = t; k < 2048; k += 256) keys[base + k] = s[k];
}

// ---------------------------------------------------------------------------
__global__ __launch_bounds__(256) void gather_sorted(
    const unsigned long long* __restrict__ keys, const float4* __restrict__ boxes,
    float4* __restrict__ box_s, unsigned long long* __restrict__ validw)
{
    int s = blockIdx.x * 256 + threadIdx.x;
    bool valid = false;
    if (s < PRE) {
        unsigned idx = (unsigned)(keys[s] & 0xffffffffull);
        float4 b = boxes[idx];
        box_s[s] = b;
        valid = ((b.z - b.x) >= 16.f) && ((b.w - b.y) >= 16.f);
    }
    unsigned long long bal = __ballot(valid);
    if ((threadIdx.x & 63) == 0) validw[s >> 6] = bal;
}

// ---------------------------------------------------------------------------
__global__ __launch_bounds__(128) void nms_mask(
    const float4* __restrict__ box_s, unsigned long long* __restrict__ mask)
{
    const int i = blockIdx.x;
    const int w = threadIdx.x;
    if (w >= NW) return;
    float4 bi = box_s[i];
    float areai = (bi.z - bi.x) * (bi.w - bi.y);
    unsigned long long m = 0ull;
    const int j0 = w * 64;
    if (j0 + 63 > i) {
#pragma unroll 4
        for (int b = 0; b < 64; ++b) {
            int j = j0 + b;
            if (j <= i || j >= PRE) continue;
            float4 bj = box_s[j];
            float areaj = (bj.z - bj.x) * (bj.w - bj.y);
            float iy1 = fmaxf(bi.x, bj.x), ix1 = fmaxf(bi.y, bj.y);
            float iy2 = fminf(bi.z, bj.z), ix2 = fminf(bi.w, bj.w);
            float inter = fmaxf(iy2 - iy1, 0.f) * fmaxf(ix2 - ix1, 0.f);
            float iou = inter / (areai + areaj - inter + 1e-8f);
            if (iou > 0.7f) m |= (1ull << b);
        }
    }
    mask[(size_t)i * MASKW + w] = m;
}

// ---------------------------------------------------------------------------
__global__ __launch_bounds__(64) void nms_scan(
    const unsigned long long* __restrict__ mask,
    const unsigned long long* __restrict__ validw,
    unsigned long long* __restrict__ keepw)
{
    const int l = threadIdx.x;
    unsigned long long r0 = ~validw[l];
    unsigned long long r1 = (l < NW - 64) ? ~validw[64 + l] : ~0ull;

    unsigned long long p0[16], p1[16];
#pragma unroll
    for (int k = 0; k < 16; ++k) {
        p0[k] = mask[(size_t)k * MASKW + l];
        p1[k] = (l < NW - 64) ? mask[(size_t)k * MASKW + 64 + l] : 0ull;
    }
    int kept = 0;
    for (int w = 0; w < NW && kept < POST; ++w) {
        unsigned long long Wc = (w < 64) ? __shfl(r0, w) : __shfl(r1, w - 64);
#pragma unroll 16
        for (int b = 0; b < 64; ++b) {
            int i = w * 64 + b;
            if (i >= PRE) break;
            int slot = i & 15;
            unsigned long long m0 = p0[slot], m1 = p1[slot];
            int nxt = i + 16;
            if (nxt < PRE) {
                p0[slot] = mask[(size_t)nxt * MASKW + l];
                p1[slot] = (l < NW - 64) ? mask[(size_t)nxt * MASKW + 64 + l] : 0ull;
            }
            if (!((Wc >> b) & 1ull)) {
                r0 |= m0; r1 |= m1;
                Wc = (w < 64) ? __shfl(r0, w) : __shfl(r1, w - 64);
                ++kept;
            }
        }
    }
    keepw[l] = ~r0;
    if (l < NW - 64) keepw[64 + l] = ~r1;
}

// ---------------------------------------------------------------------------
__global__ __launch_bounds__(256) void out_gather(
    const unsigned long long* __restrict__ keepw,
    const float4* __restrict__ box_s, float* __restrict__ outp)
{
    __shared__ unsigned long long kw_s[NW];
    __shared__ int prefix[NW];
    const int t = threadIdx.x;
    if (t < NW) kw_s[t] = keepw[t];
    __syncthreads();
    if (t == 0) {
        int cum = 0;
        for (int w = 0; w < NW; ++w) { prefix[w] = cum; cum += __popcll(kw_s[w]); }
    }
    for (int k = t; k < POST * 4; k += 256) outp[k] = 0.f;
    __syncthreads();
    for (int i = t; i < PRE; i += 256) {
        int w = i >> 6, b = i & 63;
        unsigned long long kw = kw_s[w];
        if ((kw >> b) & 1ull) {
            int rank = prefix[w] + __popcll(kw & ((1ull << b) - 1ull));
            if (rank < POST) {
                float4 bx = box_s[i];
                outp[rank * 4 + 0] = bx.x;
                outp[rank * 4 + 1] = bx.y;
                outp[rank * 4 + 2] = bx.z;
                outp[rank * 4 + 3] = bx.w;
            }
        }
    }
}

// ---------------------------------------------------------------------------
extern "C" void kernel_launch(void* const* d_in, const int* in_sizes, int n_in,
                              void* d_out, int out_size, void* d_ws, size_t ws_size,
                              hipStream_t stream)
{
    const float* x      = (const float*)d_in[0];
    const int*   ishape = (const int*)  d_in[1];
    const float* am     = (const float*)d_in[2];
    const float* w1   = (const float*)d_in[6];
    const float* b1   = (const float*)d_in[7];
    const float* wcls = (const float*)d_in[8];
    const float* bcls = (const float*)d_in[9];
    const float* wbox = (const float*)d_in[10];
    const float* bbox = (const float*)d_in[11];
    float* out = (float*)d_out;

    char* ws = (char*)d_ws;
    size_t off = 0;
    float* y = (float*)(ws + off);                    off += (size_t)COUT * NPIX * 4;
    float* wt = (float*)(ws + off);                   off += (size_t)K9 * COUT * 4;
    float4* boxes = (float4*)(ws + off);              off += (size_t)NANCH * 16;
    unsigned long long* keys = (unsigned long long*)(ws + off); off += (size_t)SORTN * 8;
    float4* box_s = (float4*)(ws + off);              off += (size_t)PRE * 16;
    unsigned long long* validw = (unsigned long long*)(ws + off); off += 96 * 8;
    unsigned long long* keepw  = (unsigned long long*)(ws + off); off += 96 * 8;
    unsigned long long* maskb  = (unsigned long long*)(ws + off); off += (size_t)PRE * MASKW * 8;

    wtrans<<<dim3(K9 / 32, COUT / 32), 256, 0, stream>>>(w1, wt);
    conv3x3_relu<<<dim3(169, 4), 256, 0, stream>>>(x, wt, b1, y);
    rpn_head<<<SORTN / 256, 256, 0, stream>>>(y, wcls, bcls, wbox, bbox, am, ishape,
                                              out, out + NANCH, boxes, keys);
    bitonic_local<<<SORTN / 2048, 256, 0, stream>>>(keys);
    for (int L = 4096; L <= SORTN; L <<= 1) {
        for (int d = L >> 1; d >= 2048; d >>= 1)
            bitonic_gpass<<<SORTN / 512, 256, 0, stream>>>(keys, L, d);
        bitonic_lmerge<<<SORTN / 2048, 256, 0, stream>>>(keys, L);
    }
    gather_sorted<<<24, 256, 0, stream>>>(keys, boxes, box_s, validw);
    nms_mask<<<PRE, 128, 0, stream>>>(box_s, maskb);
    nms_scan<<<1, 64, 0, stream>>>(maskb, validw, keepw);
    out_gather<<<1, 256, 0, stream>>>(keepw, box_s, out + (size_t)NANCH * 5);
}

// Round 6
// 1601.945 us; speedup vs baseline: 2.8121x; 2.8121x over previous
//
#include <hip/hip_runtime.h>
#include <hip/hip_fp16.h>
#include <stdint.h>

#define HH 100
#define WW 100
#define NPIX 10000
#define CIN 1024
#define COUT 1024
#define NA 9
#define NANCH 90000
#define PRE 6000
#define POST 300
#define SORTN 131072
#define MASKW 96
#define NW 94
#define K9 9216          // CIN*9
#define SPAD 10404       // 102*102 padded pixel rows
#define WSCALE 1024.0f   // exact pow2 pre-scale for w split (avoids fp16 subnormals)

typedef unsigned short u16;
typedef _Float16 f16x8 __attribute__((ext_vector_type(8)));
typedef float f32x4 __attribute__((ext_vector_type(4)));

// ---------------------------------------------------------------------------
// xsplit: x fp32 [ci][px] -> xt1/xt2 fp16 [spx][ci] (padded-pixel major,
// ci contiguous). x = x1 + x2 + O(2^-22 x). Border rows zeroed by xborder.
// ---------------------------------------------------------------------------
__global__ __launch_bounds__(256) void xsplit(
    const float* __restrict__ x, u16* __restrict__ xt1, u16* __restrict__ xt2)
{
    __shared__ unsigned sh[32][257];   // [px_local][ci_local]: h1<<16 | h2
    const int t = threadIdx.x;
    const int px0 = blockIdx.x * 32;
    const int ci0 = blockIdx.y * 256;
    for (int it = 0; it < 32; ++it) {
        int idx = it * 256 + t;
        int a = idx >> 5, b = idx & 31;
        int p = px0 + b;
        float v = (p < NPIX) ? x[(size_t)(ci0 + a) * NPIX + p] : 0.f;
        __half h1 = __float2half_rn(v);
        __half h2 = __float2half_rn(v - __half2float(h1));
        sh[b][a] = ((unsigned)__half_as_ushort(h1) << 16) | __half_as_ushort(h2);
    }
    __syncthreads();
    for (int it = 0; it < 8; ++it) {
        int u = it * 256 + t;
        int pl = u >> 6, cq = u & 63;
        int p = px0 + pl;
        if (p >= NPIX) continue;
        int r = p / 100, c = p - r * 100;
        int spx = (r + 1) * 102 + (c + 1);
        unsigned w0 = sh[pl][cq * 4 + 0], w1 = sh[pl][cq * 4 + 1];
        unsigned w2 = sh[pl][cq * 4 + 2], w3 = sh[pl][cq * 4 + 3];
        ushort4 v1 = make_ushort4((u16)(w0 >> 16), (u16)(w1 >> 16), (u16)(w2 >> 16), (u16)(w3 >> 16));
        ushort4 v2 = make_ushort4((u16)(w0 & 0xffff), (u16)(w1 & 0xffff), (u16)(w2 & 0xffff), (u16)(w3 & 0xffff));
        size_t o = (size_t)spx * 1024 + ci0 + cq * 4;
        *(ushort4*)&xt1[o] = v1;
        *(ushort4*)&xt2[o] = v2;
    }
}

__global__ __launch_bounds__(256) void xborder(u16* __restrict__ xt1, u16* __restrict__ xt2)
{
    const int idx = blockIdx.x;            // 0..403
    int spx;
    if (idx < 102) spx = idx;
    else if (idx < 204) spx = 10302 + (idx - 102);
    else { int k = idx - 204; spx = (1 + (k >> 1)) * 102 + (k & 1) * 101; }
    const int t = threadIdx.x;
    size_t o = (size_t)spx * 1024 + t * 4;
    *(ushort4*)&xt1[o] = make_ushort4(0, 0, 0, 0);
    *(ushort4*)&xt2[o] = make_ushort4(0, 0, 0, 0);
}

// ---------------------------------------------------------------------------
// wsplit: w1 fp32 [co][ci*9+tap] -> wp1/wp2 fp16 [tap][co][ci], scaled x1024.
// ---------------------------------------------------------------------------
__global__ __launch_bounds__(256) void wsplit(
    const float* __restrict__ w1, u16* __restrict__ wp1, u16* __restrict__ wp2)
{
    __shared__ float sw[K9];
    const int t = threadIdx.x;
    const int co = blockIdx.x;
    for (int it = 0; it < 36; ++it)
        sw[it * 256 + t] = w1[(size_t)co * K9 + it * 256 + t];
    __syncthreads();
    for (int tap = 0; tap < 9; ++tap) {
        for (int it = 0; it < 4; ++it) {
            int ci = it * 256 + t;
            float v = sw[ci * 9 + tap] * WSCALE;
            __half h1 = __float2half_rn(v);
            __half h2 = __float2half_rn(v - __half2float(h1));
            size_t o = (size_t)tap * (COUT * 1024) + (size_t)co * 1024 + ci;
            wp1[o] = __half_as_ushort(h1);
            wp2[o] = __half_as_ushort(h2);
        }
    }
}

// ---------------------------------------------------------------------------
// conv_mfma: 3x3 conv via fp16-split MFMA. Block 128co x 128px, 256 thr,
// wave tile 64x64 (m4 x n4). K = 9 taps x 1024 ci, kstep 32.
// 4 products: A1B1 + A1B2 + A2B1 + A2B2; result scaled by 1/1024.
// LDS rows: 32 ci (64B) + 16B pad = 80B.
// ---------------------------------------------------------------------------
__global__ __launch_bounds__(256, 2) void conv_mfma(
    const u16* __restrict__ xt1, const u16* __restrict__ xt2,
    const u16* __restrict__ wp1, const u16* __restrict__ wp2,
    const float* __restrict__ b1, float* __restrict__ y)
{
    __shared__ __align__(16) char lds[40960];   // A planes @0/@10240; B @20480/@30720
    const int t = threadIdx.x;
    const int co0 = blockIdx.x * 128;
    const int px0 = blockIdx.y * 128;
    const int wave = t >> 6, lane = t & 63;
    const int wm = (wave >> 1) * 64;
    const int wn = (wave & 1) * 64;

    int gA[2], gB[2], lA[2], lB[2];
#pragma unroll
    for (int q = 0; q < 2; ++q) {
        int u = t + q * 256;
        int row = u >> 2, ch = u & 3;
        gA[q] = (co0 + row) * 1024 + ch * 8;
        int p = px0 + row; if (p > NPIX - 1) p = NPIX - 1;
        int r = p / 100, c = p - r * 100;
        gB[q] = ((r + 1) * 102 + c + 1) * 1024 + ch * 8;
        lA[q] = row * 80 + ch * 16;
        lB[q] = 20480 + row * 80 + ch * 16;
    }
    const int fA = (wm + (lane & 15)) * 80 + (lane >> 4) * 16;
    const int fB = 20480 + (wn + (lane & 15)) * 80 + (lane >> 4) * 16;

    f32x4 acc[4][4] = {};

    for (int tap = 0; tap < 9; ++tap) {
        const int dy = tap / 3;
        const int toff = ((dy - 1) * 102 + (tap - dy * 3) - 1) * 1024;
        const int wtap = tap << 20;
        for (int ci0 = 0; ci0 < 1024; ci0 += 32) {
            __syncthreads();
#pragma unroll
            for (int q = 0; q < 2; ++q) {
                uint4 a1 = *(const uint4*)(wp1 + (gA[q] + wtap + ci0));
                uint4 a2 = *(const uint4*)(wp2 + (gA[q] + wtap + ci0));
                uint4 b1v = *(const uint4*)(xt1 + (gB[q] + toff + ci0));
                uint4 b2v = *(const uint4*)(xt2 + (gB[q] + toff + ci0));
                *(uint4*)(lds + lA[q])         = a1;
                *(uint4*)(lds + lA[q] + 10240) = a2;
                *(uint4*)(lds + lB[q])         = b1v;
                *(uint4*)(lds + lB[q] + 10240) = b2v;
            }
            __syncthreads();
            f16x8 A1[4], A2[4], B1[4], B2[4];
#pragma unroll
            for (int mi = 0; mi < 4; ++mi) {
                A1[mi] = *(const f16x8*)(lds + fA + mi * 1280);
                A2[mi] = *(const f16x8*)(lds + fA + mi * 1280 + 10240);
            }
#pragma unroll
            for (int ni = 0; ni < 4; ++ni) {
                B1[ni] = *(const f16x8*)(lds + fB + ni * 1280);
                B2[ni] = *(const f16x8*)(lds + fB + ni * 1280 + 10240);
            }
#pragma unroll
            for (int mi = 0; mi < 4; ++mi)
#pragma unroll
                for (int ni = 0; ni < 4; ++ni) {
                    acc[mi][ni] = __builtin_amdgcn_mfma_f32_16x16x32_f16(A1[mi], B1[ni], acc[mi][ni], 0, 0, 0);
                    acc[mi][ni] = __builtin_amdgcn_mfma_f32_16x16x32_f16(A1[mi], B2[ni], acc[mi][ni], 0, 0, 0);
                    acc[mi][ni] = __builtin_amdgcn_mfma_f32_16x16x32_f16(A2[mi], B1[ni], acc[mi][ni], 0, 0, 0);
                    acc[mi][ni] = __builtin_amdgcn_mfma_f32_16x16x32_f16(A2[mi], B2[ni], acc[mi][ni], 0, 0, 0);
                }
        }
    }

    // epilogue: D row=(lane>>4)*4+reg (co), col=lane&15 (px); descale + bias + relu
    const int q4 = (lane >> 4) * 4, nl = lane & 15;
    const float inv = 1.0f / WSCALE;
#pragma unroll
    for (int mi = 0; mi < 4; ++mi) {
        const int cob = co0 + wm + mi * 16 + q4;
        const float bb0 = b1[cob + 0], bb1 = b1[cob + 1];
        const float bb2 = b1[cob + 2], bb3 = b1[cob + 3];
#pragma unroll
        for (int ni = 0; ni < 4; ++ni) {
            const int px = px0 + wn + ni * 16 + nl;
            if (px < NPIX) {
                y[(size_t)(cob + 0) * NPIX + px] = fmaxf(acc[mi][ni][0] * inv + bb0, 0.f);
                y[(size_t)(cob + 1) * NPIX + px] = fmaxf(acc[mi][ni][1] * inv + bb1, 0.f);
                y[(size_t)(cob + 2) * NPIX + px] = fmaxf(acc[mi][ni][2] * inv + bb2, 0.f);
                y[(size_t)(cob + 3) * NPIX + px] = fmaxf(acc[mi][ni][3] * inv + bb3, 0.f);
            }
        }
    }
}

// ---------------------------------------------------------------------------
// rpn_head: fused 1x1 heads + sigmoid + box decode + clip + sort-key pack.
// ---------------------------------------------------------------------------
__global__ __launch_bounds__(256) void rpn_head(
    const float* __restrict__ y,
    const float* __restrict__ wcls, const float* __restrict__ bcls,
    const float* __restrict__ wbox, const float* __restrict__ bbox,
    const float* __restrict__ am, const int* __restrict__ ishape,
    float* __restrict__ out_scores, float* __restrict__ out_deltas,
    float4* __restrict__ boxes, unsigned long long* __restrict__ keys)
{
    __shared__ float wlds[8][46];
    const int t = threadIdx.x;
    const int i = blockIdx.x * 256 + t;
    if (blockIdx.x * 256 >= NANCH) {
        if (i < SORTN) keys[i] = 0ull;
        return;
    }
    const int ia = (i < NANCH) ? i : (NANCH - 1);
    const int p = ia / NA, a = ia % NA;
    float acc[5] = {0.f, 0.f, 0.f, 0.f, 0.f};
    for (int c0 = 0; c0 < CIN; c0 += 8) {
        __syncthreads();
        for (int e = t; e < 360; e += 256) {
            int ch = e % 45, cc = e / 45;
            wlds[cc][ch] = (ch < 9) ? wcls[ch * CIN + c0 + cc]
                                    : wbox[(ch - 9) * CIN + c0 + cc];
        }
        __syncthreads();
#pragma unroll
        for (int cc = 0; cc < 8; ++cc) {
            float yv = y[(size_t)(c0 + cc) * NPIX + p];
            acc[0] += yv * wlds[cc][a];
#pragma unroll
            for (int c = 0; c < 4; ++c)
                acc[1 + c] += yv * wlds[cc][9 + 4 * a + c];
        }
    }
    if (i >= NANCH) { if (i < SORTN) keys[i] = 0ull; return; }

    float logit = acc[0] + bcls[a];
    float score = 1.f / (1.f + expf(-logit));
    float d0 = acc[1] + bbox[4 * a + 0];
    float d1 = acc[2] + bbox[4 * a + 1];
    float d2 = acc[3] + bbox[4 * a + 2];
    float d3 = acc[4] + bbox[4 * a + 3];
    out_scores[i] = score;
    out_deltas[i * 4 + 0] = d0;
    out_deltas[i * 4 + 1] = d1;
    out_deltas[i * 4 + 2] = d2;
    out_deltas[i * 4 + 3] = d3;

    float cy = am[i * 4 + 0], cx = am[i * 4 + 1];
    float ah = am[i * 4 + 2], aw = am[i * 4 + 3];
    float ctry = cy + d0 * ah, ctrx = cx + d1 * aw;
    float hh = ah * expf(d2), ww = aw * expf(d3);
    float y1 = ctry - 0.5f * hh, x1 = ctrx - 0.5f * ww;
    float y2 = ctry + 0.5f * hh, x2 = ctrx + 0.5f * ww;
    float imh = (float)ishape[1], imw = (float)ishape[2];
    y1 = fmaxf(y1, 0.f); x1 = fmaxf(x1, 0.f);
    y2 = fminf(y2, imh); x2 = fminf(x2, imw);
    boxes[i] = make_float4(y1, x1, y2, x2);
    unsigned sb = __float_as_uint(score);
    keys[i] = ((unsigned long long)sb << 32) | (unsigned)i;
}

// ---------------------------------------------------------------------------
// Bitonic sort (descending) of SORTN u64 keys.
// ---------------------------------------------------------------------------
__global__ __launch_bounds__(256) void bitonic_local(unsigned long long* keys)
{
    __shared__ unsigned long long s[2048];
    const int base = blockIdx.x * 2048, t = threadIdx.x;
    for (int k = t; k < 2048; k += 256) s[k] = keys[base + k];
    for (int L = 2; L <= 2048; L <<= 1) {
        for (int d = L >> 1; d >= 1; d >>= 1) {
            __syncthreads();
            for (int pr = t; pr < 1024; pr += 256) {
                int i = ((pr & ~(d - 1)) << 1) | (pr & (d - 1));
                int j = i + d;
                bool desc = (((base + i) & L) == 0);
                unsigned long long va = s[i], vb = s[j];
                bool sw = desc ? (va < vb) : (va > vb);
                if (sw) { s[i] = vb; s[j] = va; }
            }
        }
    }
    __syncthreads();
    for (int k = t; k < 2048; k += 256) keys[base + k] = s[k];
}

__global__ __launch_bounds__(256) void bitonic_gpass(unsigned long long* keys, int L, int d)
{
    int pr = blockIdx.x * 256 + threadIdx.x;
    int i = ((pr & ~(d - 1)) << 1) | (pr & (d - 1));
    int j = i + d;
    bool desc = ((i & L) == 0);
    unsigned long long va = keys[i], vb = keys[j];
    bool sw = desc ? (va < vb) : (va > vb);
    if (sw) { keys[i] = vb; keys[j] = va; }
}

__global__ __launch_bounds__(256) void bitonic_lmerge(unsigned long long* keys, int L)
{
    __shared__ unsigned long long s[2048];
    const int base = blockIdx.x * 2048, t = threadIdx.x;
    for (int k = t; k < 2048; k += 256) s[k] = keys[base + k];
    const bool desc = ((base & L) == 0);
    for (int d = 1024; d >= 1; d >>= 1) {
        __syncthreads();
        for (int pr = t; pr < 1024; pr += 256) {
            int i = ((pr & ~(d - 1)) << 1) | (pr & (d - 1));
            int j = i + d;
            unsigned long long va = s[i], vb = s[j];
            bool sw = desc ? (va < vb) : (va > vb);
            if (sw) { s[i] = vb; s[j] = va; }
        }
    }
    __syncthreads();
    for (int k = t; k < 2048; k += 256) keys[base + k] = s[k];
}

// ---------------------------------------------------------------------------
__global__ __launch_bounds__(256) void gather_sorted(
    const unsigned long long* __restrict__ keys, const float4* __restrict__ boxes,
    float4* __restrict__ box_s, unsigned long long* __restrict__ validw)
{
    int s = blockIdx.x * 256 + threadIdx.x;
    bool valid = false;
    if (s < PRE) {
        unsigned idx = (unsigned)(keys[s] & 0xffffffffull);
        float4 b = boxes[idx];
        box_s[s] = b;
        valid = ((b.z - b.x) >= 16.f) && ((b.w - b.y) >= 16.f);
    }
    unsigned long long bal = __ballot(valid);
    if ((threadIdx.x & 63) == 0) validw[s >> 6] = bal;
}

// ---------------------------------------------------------------------------
__global__ __launch_bounds__(128) void nms_mask(
    const float4* __restrict__ box_s, unsigned long long* __restrict__ mask)
{
    const int i = blockIdx.x;
    const int w = threadIdx.x;
    if (w >= NW) return;
    float4 bi = box_s[i];
    float areai = (bi.z - bi.x) * (bi.w - bi.y);
    unsigned long long m = 0ull;
    const int j0 = w * 64;
    if (j0 + 63 > i) {
#pragma unroll 4
        for (int b = 0; b < 64; ++b) {
            int j = j0 + b;
            if (j <= i || j >= PRE) continue;
            float4 bj = box_s[j];
            float areaj = (bj.z - bj.x) * (bj.w - bj.y);
            float iy1 = fmaxf(bi.x, bj.x), ix1 = fmaxf(bi.y, bj.y);
            float iy2 = fminf(bi.z, bj.z), ix2 = fminf(bi.w, bj.w);
            float inter = fmaxf(iy2 - iy1, 0.f) * fmaxf(ix2 - ix1, 0.f);
            float iou = inter / (areai + areaj - inter + 1e-8f);
            if (iou > 0.7f) m |= (1ull << b);
        }
    }
    mask[(size_t)i * MASKW + w] = m;
}

// ---------------------------------------------------------------------------
__global__ __launch_bounds__(64) void nms_scan(
    const unsigned long long* __restrict__ mask,
    const unsigned long long* __restrict__ validw,
    unsigned long long* __restrict__ keepw)
{
    const int l = threadIdx.x;
    unsigned long long r0 = ~validw[l];
    unsigned long long r1 = (l < NW - 64) ? ~validw[64 + l] : ~0ull;

    unsigned long long p0[16], p1[16];
#pragma unroll
    for (int k = 0; k < 16; ++k) {
        p0[k] = mask[(size_t)k * MASKW + l];
        p1[k] = (l < NW - 64) ? mask[(size_t)k * MASKW + 64 + l] : 0ull;
    }
    int kept = 0;
    for (int w = 0; w < NW && kept < POST; ++w) {
        unsigned long long Wc = (w < 64) ? __shfl(r0, w) : __shfl(r1, w - 64);
#pragma unroll 16
        for (int b = 0; b < 64; ++b) {
            int i = w * 64 + b;
            if (i >= PRE) break;
            int slot = i & 15;
            unsigned long long m0 = p0[slot], m1 = p1[slot];
            int nxt = i + 16;
            if (nxt < PRE) {
                p0[slot] = mask[(size_t)nxt * MASKW + l];
                p1[slot] = (l < NW - 64) ? mask[(size_t)nxt * MASKW + 64 + l] : 0ull;
            }
            if (!((Wc >> b) & 1ull)) {
                r0 |= m0; r1 |= m1;
                Wc = (w < 64) ? __shfl(r0, w) : __shfl(r1, w - 64);
                ++kept;
            }
        }
    }
    keepw[l] = ~r0;
    if (l < NW - 64) keepw[64 + l] = ~r1;
}

// ---------------------------------------------------------------------------
__global__ __launch_bounds__(256) void out_gather(
    const unsigned long long* __restrict__ keepw,
    const float4* __restrict__ box_s, float* __restrict__ outp)
{
    __shared__ unsigned long long kw_s[NW];
    __shared__ int prefix[NW];
    const int t = threadIdx.x;
    if (t < NW) kw_s[t] = keepw[t];
    __syncthreads();
    if (t == 0) {
        int cum = 0;
        for (int w = 0; w < NW; ++w) { prefix[w] = cum; cum += __popcll(kw_s[w]); }
    }
    for (int k = t; k < POST * 4; k += 256) outp[k] = 0.f;
    __syncthreads();
    for (int i = t; i < PRE; i += 256) {
        int w = i >> 6, b = i & 63;
        unsigned long long kw = kw_s[w];
        if ((kw >> b) & 1ull) {
            int rank = prefix[w] + __popcll(kw & ((1ull << b) - 1ull));
            if (rank < POST) {
                float4 bx = box_s[i];
                outp[rank * 4 + 0] = bx.x;
                outp[rank * 4 + 1] = bx.y;
                outp[rank * 4 + 2] = bx.z;
                outp[rank * 4 + 3] = bx.w;
            }
        }
    }
}

// ---------------------------------------------------------------------------
extern "C" void kernel_launch(void* const* d_in, const int* in_sizes, int n_in,
                              void* d_out, int out_size, void* d_ws, size_t ws_size,
                              hipStream_t stream)
{
    const float* x      = (const float*)d_in[0];
    const int*   ishape = (const int*)  d_in[1];
    const float* am     = (const float*)d_in[2];
    const float* w1   = (const float*)d_in[6];
    const float* b1   = (const float*)d_in[7];
    const float* wcls = (const float*)d_in[8];
    const float* bcls = (const float*)d_in[9];
    const float* wbox = (const float*)d_in[10];
    const float* bbox = (const float*)d_in[11];
    float* out = (float*)d_out;

    char* ws = (char*)d_ws;
    size_t off = 0;
    float* y  = (float*)(ws + off);  off += (size_t)COUT * NPIX * 4;
    u16* xt1  = (u16*)(ws + off);    off += (size_t)SPAD * 1024 * 2;
    u16* xt2  = (u16*)(ws + off);    off += (size_t)SPAD * 1024 * 2;
    u16* wp1  = (u16*)(ws + off);    off += (size_t)9 * COUT * 1024 * 2;
    u16* wp2  = (u16*)(ws + off);    off += (size_t)9 * COUT * 1024 * 2;
    float4* boxes = (float4*)(ws + off);              off += (size_t)NANCH * 16;
    unsigned long long* keys = (unsigned long long*)(ws + off); off += (size_t)SORTN * 8;
    float4* box_s = (float4*)(ws + off);              off += (size_t)PRE * 16;
    unsigned long long* validw = (unsigned long long*)(ws + off); off += 96 * 8;
    unsigned long long* keepw  = (unsigned long long*)(ws + off); off += 96 * 8;
    unsigned long long* maskb  = (unsigned long long*)(ws + off); off += (size_t)PRE * MASKW * 8;

    xsplit<<<dim3(313, 4), 256, 0, stream>>>(x, xt1, xt2);
    xborder<<<404, 256, 0, stream>>>(xt1, xt2);
    wsplit<<<COUT, 256, 0, stream>>>(w1, wp1, wp2);
    conv_mfma<<<dim3(8, 79), 256, 0, stream>>>(xt1, xt2, wp1, wp2, b1, y);
    rpn_head<<<SORTN / 256, 256, 0, stream>>>(y, wcls, bcls, wbox, bbox, am, ishape,
                                              out, out + NANCH, boxes, keys);
    bitonic_local<<<SORTN / 2048, 256, 0, stream>>>(keys);
    for (int L = 4096; L <= SORTN; L <<= 1) {
        for (int d = L >> 1; d >= 2048; d >>= 1)
            bitonic_gpass<<<SORTN / 512, 256, 0, stream>>>(keys, L, d);
        bitonic_lmerge<<<SORTN / 2048, 256, 0, stream>>>(keys, L);
    }
    gather_sorted<<<24, 256, 0, stream>>>(keys, boxes, box_s, validw);
    nms_mask<<<PRE, 128, 0, stream>>>(box_s, maskb);
    nms_scan<<<1, 64, 0, stream>>>(maskb, validw, keepw);
    out_gather<<<1, 256, 0, stream>>>(keepw, box_s, out + (size_t)NANCH * 5);
}